// Round 1
// 332.471 us; speedup vs baseline: 1.3947x; 1.3947x over previous
//
#include <hip/hip_runtime.h>

#define BB 8
#define SS 4096
#define HIDD 1024
#define HH 16
#define DHH 64

// K1: weff[o][i], o<16: sum_d aw[o,d]*Wq[o*64+d, i]; o>=16: same with Wk.
// wq_f and wk_f are adjacent in ws => weff = wq_f is [32][1024].
// grid (4, 16, 2), block 256
__global__ __launch_bounds__(256) void k_prep(const float* __restrict__ Wq,
                                              const float* __restrict__ Wk,
                                              const float* __restrict__ aw,
                                              float* __restrict__ wq_f,
                                              float* __restrict__ wk_f) {
    int i = blockIdx.x * 256 + threadIdx.x;
    int h = blockIdx.y;
    const float* W = blockIdx.z ? Wk : Wq;
    float* outp = blockIdx.z ? wk_f : wq_f;
    float acc = 0.f;
#pragma unroll
    for (int d = 0; d < DHH; ++d) {
        acc += aw[h * DHH + d] * W[(size_t)(h * DHH + d) * HIDD + i];
    }
    outp[h * HIDD + i] = acc;
}

// K2 v4: tall-skinny GEMM  scores[32768 rows][32 outs] = hid x weff^T.
// Out-split: blockIdx.x=0 -> q heads 0..15, =1 -> k heads 16..31. Each block
// 256 thr = 4 waves, wave owns 4 outs, lane = row (64 rows/block).
// Grid (2, 512) -> 1024 blocks -> 4 blocks/CU (LDS 33KB) = 4 waves/SIMD.
// Register-prefetch of next chunk issued AFTER the post-staging barrier so
// the vmcnt drain at the next barrier is free (loads finish under compute).
#define KC 128
#define LSTR 129
__global__ __launch_bounds__(256, 4) void k_scores(const float* __restrict__ hid,
                                                   const float* __restrict__ mask,
                                                   const float* __restrict__ weff,
                                                   float* __restrict__ qsb,
                                                   float* __restrict__ ksb) {
    __shared__ float sh[64 * LSTR];

    const int t    = threadIdx.x;
    const int wave = t >> 6;
    const int lane = t & 63;
    const int obase = __builtin_amdgcn_readfirstlane(blockIdx.x * 16 + wave * 4);

    const int row  = blockIdx.y * 64 + lane;       // global row (b*4096+s)
    const size_t gbase = (size_t)blockIdx.y * 64 * HIDD;

    float acc[4] = {0.f, 0.f, 0.f, 0.f};

    float4 stg[8];
#pragma unroll
    for (int j = 0; j < 8; ++j) {
        int f  = j * 256 + t;
        int r  = f >> 5;
        int c4 = f & 31;
        stg[j] = *reinterpret_cast<const float4*>(
            hid + gbase + (size_t)r * HIDD + c4 * 4);
    }

    for (int chunk = 0; chunk < HIDD / KC; ++chunk) {
        __syncthreads();                    // prev compute done; LDS free
#pragma unroll
        for (int j = 0; j < 8; ++j) {
            int f  = j * 256 + t;
            int r  = f >> 5;
            int c4 = f & 31;
            float* d = sh + r * LSTR + c4 * 4;
            d[0] = stg[j].x; d[1] = stg[j].y; d[2] = stg[j].z; d[3] = stg[j].w;
        }
        __syncthreads();                    // LDS ready
        if (chunk + 1 < HIDD / KC) {        // prefetch next chunk (hides under compute)
#pragma unroll
            for (int j = 0; j < 8; ++j) {
                int f  = j * 256 + t;
                int r  = f >> 5;
                int c4 = f & 31;
                stg[j] = *reinterpret_cast<const float4*>(
                    hid + gbase + (size_t)r * HIDD + (chunk + 1) * KC + c4 * 4);
            }
        }

        const float* wc = weff + chunk * KC;
#pragma unroll 8
        for (int k = 0; k < KC; k += 4) {
            float h0 = sh[lane * LSTR + k];
            float h1 = sh[lane * LSTR + k + 1];
            float h2 = sh[lane * LSTR + k + 2];
            float h3 = sh[lane * LSTR + k + 3];
#pragma unroll
            for (int o = 0; o < 4; ++o) {
                float4 wv = *reinterpret_cast<const float4*>(
                    wc + (size_t)(obase + o) * HIDD + k);
                acc[o] += h0 * wv.x + h1 * wv.y + h2 * wv.z + h3 * wv.w;
            }
        }
    }

    float m = mask[row];               // mask is (B,1,1,S) = flat 32768
#pragma unroll
    for (int o = 0; o < 4; ++o) acc[o] *= m;

    float4 v = make_float4(acc[0], acc[1], acc[2], acc[3]);
    if (blockIdx.x == 0) {
        *reinterpret_cast<float4*>(qsb + (size_t)row * 16 + obase) = v;
    } else {
        *reinterpret_cast<float4*>(ksb + (size_t)row * 20 + (obase - 16)) = v;
        if (obase == 16) ksb[(size_t)row * 20 + 16] = m;
    }
}

// K3 v2: NO atomics. part[schunk][b][17][1024]: partial over 128 s-rows of
// ksh (16 ch) + hsum (mask ch). grid (32, 2, 8), block 256, thread owns 2 cols.
// unroll 8 -> 8 independent global float2 loads in flight per group.
__global__ __launch_bounds__(256) void k_ksh(const float* __restrict__ hid,
                                             const float* __restrict__ ksb,
                                             float* __restrict__ part) {
    int b  = blockIdx.z;
    int i  = blockIdx.y * 512 + threadIdx.x * 2;
    int s0 = blockIdx.x * 128;

    float acc0[17], acc1[17];
#pragma unroll
    for (int c = 0; c < 17; ++c) { acc0[c] = 0.f; acc1[c] = 0.f; }

    const float* hb = hid + (size_t)(b * SS + s0) * HIDD + i;
    const float* sb = ksb + (size_t)(b * SS + s0) * 20;

#pragma unroll 8
    for (int s = 0; s < 128; ++s) {
        float2 hv = *reinterpret_cast<const float2*>(hb + (size_t)s * HIDD);
        const float* sc = sb + s * 20;
#pragma unroll
        for (int c = 0; c < 17; ++c) {
            float scv = sc[c];
            acc0[c] += scv * hv.x;
            acc1[c] += scv * hv.y;
        }
    }

    float* pb = part + (((size_t)blockIdx.x * 8 + b) * 17) * 1024 + i;
#pragma unroll
    for (int c = 0; c < 17; ++c) {
        *reinterpret_cast<float2*>(pb + c * 1024) = make_float2(acc0[c], acc1[c]);
    }
}

// K3b: reduce 32 schunk partials -> ksh[b][16][1024], hsum[b][1024].
// grid 544, block 256 (544*256 = 8*17*1024 outputs exactly)
__global__ __launch_bounds__(256) void k_red(const float* __restrict__ part,
                                             float* __restrict__ ksh,
                                             float* __restrict__ hsum) {
    int gid = blockIdx.x * 256 + threadIdx.x;
    int b = gid / 17408;               // 17*1024
    int r = gid - b * 17408;
    int c = r >> 10;
    int i = r & 1023;

    float s = 0.f;
#pragma unroll 8
    for (int k = 0; k < 32; ++k)
        s += part[(((size_t)k * 8 + b) * 17 + c) * 1024 + i];

    if (c < 16) ksh[((size_t)b * 16 + c) * 1024 + i] = s;
    else        hsum[b * 1024 + i] = s;
}

// K4 v2: mvn[b,j] = (Wv[j,:]·hsum[b,:])/len;  kvn[b,j] = (Wv[j,:]·ksh[b,j/64,:])/len
// grid (8, 32), block 256: 32 j per block, 8 lanes split each 1024-dot,
// __shfl_xor reduce over the 8-lane group.
__global__ __launch_bounds__(256) void k_fin(const float* __restrict__ Wv,
                                             const float* __restrict__ mask,
                                             const float* __restrict__ hsum,
                                             const float* __restrict__ ksh,
                                             float* __restrict__ mvn,
                                             float* __restrict__ kvn) {
    int b  = blockIdx.x;
    int j  = blockIdx.y * 32 + (threadIdx.x >> 3);
    int sl = threadIdx.x & 7;

    __shared__ float red[256];
    float lsum = 0.f;
    for (int s = threadIdx.x; s < SS; s += 256) lsum += mask[b * SS + s];
    red[threadIdx.x] = lsum;
    __syncthreads();
    for (int off = 128; off; off >>= 1) {
        if (threadIdx.x < off) red[threadIdx.x] += red[threadIdx.x + off];
        __syncthreads();
    }
    float invlen = 1.0f / red[0];

    int h = j >> 6;
    const float4* w4 = reinterpret_cast<const float4*>(Wv + (size_t)j * HIDD + sl * 128);
    const float4* hv = reinterpret_cast<const float4*>(hsum + b * HIDD + sl * 128);
    const float4* kv = reinterpret_cast<const float4*>(ksh + ((size_t)b * 16 + h) * HIDD + sl * 128);

    float mv = 0.f, kvv = 0.f;
#pragma unroll
    for (int c = 0; c < 32; ++c) {
        float4 w = w4[c], a = hv[c], k2 = kv[c];
        mv  += w.x * a.x  + w.y * a.y  + w.z * a.z  + w.w * a.w;
        kvv += w.x * k2.x + w.y * k2.y + w.z * k2.z + w.w * k2.w;
    }
#pragma unroll
    for (int off = 1; off < 8; off <<= 1) {
        mv  += __shfl_xor(mv, off);
        kvv += __shfl_xor(kvv, off);
    }
    if (sl == 0) {
        mvn[b * HIDD + j] = mv * invlen;
        kvn[b * HIDD + j] = kvv * invlen;
    }
}

// K5: out[b,s,j] = q_score[b,s,j/64]*mvn[b,j] + kvn[b,j], float4 stores.
// grid 16384, block 256, 8 elems/thread
__global__ __launch_bounds__(256) void k_out(const float* __restrict__ qsb,
                                             const float* __restrict__ mvn,
                                             const float* __restrict__ kvn,
                                             float* __restrict__ outp) {
    size_t e0 = ((size_t)blockIdx.x * 256 + threadIdx.x) * 8;
    int b   = (int)(e0 >> 22);                 // 4096*1024 = 2^22
    int rem = (int)(e0 & ((1u << 22) - 1));
    int s   = rem >> 10;
    int j   = rem & 1023;

    float q = qsb[(size_t)(b * SS + s) * 16 + (j >> 6)];
    const float4* mv4 = reinterpret_cast<const float4*>(mvn + b * HIDD + j);
    const float4* kv4 = reinterpret_cast<const float4*>(kvn + b * HIDD + j);
    float4 m0 = mv4[0], m1 = mv4[1];
    float4 k0 = kv4[0], k1 = kv4[1];

    float4 o0, o1;
    o0.x = q * m0.x + k0.x;  o0.y = q * m0.y + k0.y;
    o0.z = q * m0.z + k0.z;  o0.w = q * m0.w + k0.w;
    o1.x = q * m1.x + k1.x;  o1.y = q * m1.y + k1.y;
    o1.z = q * m1.z + k1.z;  o1.w = q * m1.w + k1.w;

    float4* op = reinterpret_cast<float4*>(outp + e0);
    op[0] = o0;
    op[1] = o1;
}

extern "C" void kernel_launch(void* const* d_in, const int* in_sizes, int n_in,
                              void* d_out, int out_size, void* d_ws, size_t ws_size,
                              hipStream_t stream) {
    const float* hid  = (const float*)d_in[0];   // (B,S,HID)
    const float* mask = (const float*)d_in[1];   // (B,1,1,S)
    const float* Wq   = (const float*)d_in[2];   // (HID,HID)
    const float* Wk   = (const float*)d_in[3];
    const float* Wv   = (const float*)d_in[4];
    const float* aw   = (const float*)d_in[5];   // (H,1,DH)
    float* outp = (float*)d_out;

    float* ws   = (float*)d_ws;
    float* wq_f = ws;                       // 16384   } weff[32][1024]
    float* wk_f = wq_f + 16384;             // 16384   } (adjacent)
    float* qsb  = wk_f + 16384;             // 8*4096*16 = 524288
    float* ksb  = qsb + 524288;             // 8*4096*20 = 655360
    float* ksh  = ksb + 655360;             // 8*16*1024 = 131072
    float* hsum = ksh + 131072;             // 8*1024   = 8192
    float* mvn  = hsum + 8192;              // 8192
    float* kvn  = mvn + 8192;               // 8192
    float* part = kvn + 8192;               // 32*8*17*1024 = 4456448 (~17.8 MB)
                                            // total ws: 5,824,512 floats = 23.3 MB

    k_prep  <<<dim3(4, 16, 2), 256, 0, stream>>>(Wq, Wk, aw, wq_f, wk_f);
    k_scores<<<dim3(2, 512),   256, 0, stream>>>(hid, mask, wq_f, qsb, ksb);
    k_ksh   <<<dim3(32, 2, 8), 256, 0, stream>>>(hid, ksb, part);
    k_red   <<<dim3(544),      256, 0, stream>>>(part, ksh, hsum);
    k_fin   <<<dim3(8, 32),    256, 0, stream>>>(Wv, mask, hsum, ksh, mvn, kvn);
    k_out   <<<dim3(16384),    256, 0, stream>>>(qsb, mvn, kvn, outp);
}